// Round 6
// baseline (505.032 us; speedup 1.0000x reference)
//
#include <hip/hip_runtime.h>
#include <hip/hip_cooperative_groups.h>
#include <hip/hip_bf16.h>

namespace cg = cooperative_groups;

#define BUCKETS 32
#define BSZ 128            // tokens per bucket (4096/32)
#define DH 64
#define TEMPINV 1.3333333333333333f   // 1/0.75
#define SINK_ITERS 7
#define LOG_EPS 1e-6f
#define SCALE 0.03125f     // DIM^-0.5 = 1024^-0.5

typedef short bf16x8 __attribute__((ext_vector_type(8)));   // 8 bf16 in 4 VGPRs
typedef float f32x4 __attribute__((ext_vector_type(4)));

// ---- bf16 helpers (bit-level, RNE rounding) ----
__device__ __forceinline__ void bf8_to_f32(const uint4 x, float* f) {
    f[0] = __uint_as_float(x.x << 16);
    f[1] = __uint_as_float(x.x & 0xffff0000u);
    f[2] = __uint_as_float(x.y << 16);
    f[3] = __uint_as_float(x.y & 0xffff0000u);
    f[4] = __uint_as_float(x.z << 16);
    f[5] = __uint_as_float(x.z & 0xffff0000u);
    f[6] = __uint_as_float(x.w << 16);
    f[7] = __uint_as_float(x.w & 0xffff0000u);
}

__device__ __forceinline__ unsigned f2bf(float f) {
    unsigned x = __float_as_uint(f);
    return (x + 0x7fffu + ((x >> 16) & 1u)) >> 16;   // RNE (no NaN in this data)
}

__device__ __forceinline__ uint4 packbf8(const float* f) {
    uint4 r;
    r.x = f2bf(f[0]) | (f2bf(f[1]) << 16);
    r.y = f2bf(f[2]) | (f2bf(f[3]) << 16);
    r.z = f2bf(f[4]) | (f2bf(f[5]) << 16);
    r.w = f2bf(f[6]) | (f2bf(f[7]) << 16);
    return r;
}

// async global->LDS DMA, 16 B per lane; dest is wave-uniform base + lane*16
__device__ __forceinline__ void load_lds16(const uint4* g, uint4* l) {
    __builtin_amdgcn_global_load_lds(
        (const __attribute__((address_space(1))) unsigned int*)g,
        (__attribute__((address_space(3))) unsigned int*)l, 16, 0, 0);
}

// ============================================================
// Phase bodies (shared between cooperative mega-kernel and the
// standalone fallback kernels). All 256-thread. `sm` = LDS base.
// ============================================================

// ---- bucket-K sum for bucket-tile t = b*32+u (bksum, round-2 proven) ----
__device__ __forceinline__ void phase_bksum(
    const float* __restrict__ kptr, float* __restrict__ bkr, int t, char* sm)
{
    float4 (*part)[17] = (float4(*)[17])sm;           // 4.3 KB
    const int tid = threadIdx.x;
    const float4* k4 = (const float4*)kptr + (size_t)t * 2048;
    const int c4 = tid & 15, rg = tid >> 4;
    float4 s; s.x = 0.f; s.y = 0.f; s.z = 0.f; s.w = 0.f;
    for (int r = rg; r < 128; r += 16) {
        float4 a = k4[r * 16 + c4];
        s.x += a.x; s.y += a.y; s.z += a.z; s.w += a.w;
    }
    part[rg][c4] = s;
    __syncthreads();
    if (tid < 16) {
        float4 acc = part[0][tid];
        for (int g = 1; g < 16; ++g) {
            float4 p = part[g][tid];
            acc.x += p.x; acc.y += p.y; acc.z += p.z; acc.w += p.w;
        }
        ((float4*)bkr)[t * 16 + tid] = acc;
    }
    __syncthreads();
}

// ---- logits + wave-parallel Sinkhorn for bh=b (round-4 proven) ----
__device__ __forceinline__ void phase_sink(
    const float* __restrict__ bkrp,
    const float* __restrict__ swptr,
    const float* __restrict__ gptr,
    float* __restrict__ Rout, int b, char* sm)
{
    float (*bk)[DH]  = (float(*)[DH])sm;                       // 8 KB
    float (*swl)[BUCKETS] = (float(*)[BUCKETS])(sm + 8192);    // 8 KB
    float (*R)[BUCKETS + 1] = (float(*)[BUCKETS + 1])(sm + 16384);
    const int h = b & 15;
    const int tid = threadIdx.x;

    for (int o = tid; o < DH * BUCKETS; o += 256)
        swl[o >> 5][o & 31] = swptr[h * DH * BUCKETS + o];
    for (int o = tid; o < BUCKETS * DH; o += 256)
        bk[o >> 6][o & 63] = bkrp[b * 2048 + o];
    __syncthreads();

    for (int o = tid; o < BUCKETS * BUCKETS; o += 256) {
        const int uu = o >> 5, vv = o & 31;
        float dot = 0.f;
        for (int d = 0; d < DH; ++d) dot = fmaf(bk[uu][d], swl[d][vv], dot);
        const float g = gptr[b * 1024 + o];
        R[uu][vv] = (logf(fmaxf(dot, 0.f) + LOG_EPS) + g) * TEMPINV;
    }
    __syncthreads();

    const int rr = tid >> 3, sub = tid & 7;
    for (int it = 0; it < SINK_ITERS; ++it) {
        {
            float vals[4];
            float m = -1e30f, s = 0.f;
            #pragma unroll
            for (int q = 0; q < 4; ++q) { vals[q] = R[rr][sub * 4 + q]; m = fmaxf(m, vals[q]); }
            m = fmaxf(m, __shfl_xor(m, 1)); m = fmaxf(m, __shfl_xor(m, 2)); m = fmaxf(m, __shfl_xor(m, 4));
            #pragma unroll
            for (int q = 0; q < 4; ++q) s += expf(vals[q] - m);
            s += __shfl_xor(s, 1); s += __shfl_xor(s, 2); s += __shfl_xor(s, 4);
            const float lse = m + logf(s);
            #pragma unroll
            for (int q = 0; q < 4; ++q) R[rr][sub * 4 + q] = vals[q] - lse;
            __syncthreads();
        }
        {
            float vals[4];
            float m = -1e30f, s = 0.f;
            #pragma unroll
            for (int q = 0; q < 4; ++q) { vals[q] = R[sub * 4 + q][rr]; m = fmaxf(m, vals[q]); }
            m = fmaxf(m, __shfl_xor(m, 1)); m = fmaxf(m, __shfl_xor(m, 2)); m = fmaxf(m, __shfl_xor(m, 4));
            #pragma unroll
            for (int q = 0; q < 4; ++q) s += expf(vals[q] - m);
            s += __shfl_xor(s, 1); s += __shfl_xor(s, 2); s += __shfl_xor(s, 4);
            const float lse = m + logf(s);
            #pragma unroll
            for (int q = 0; q < 4; ++q) R[sub * 4 + q][rr] = vals[q] - lse;
            __syncthreads();
        }
    }

    for (int o = tid; o < BUCKETS * BUCKETS; o += 256) {
        const int uu = o >> 5, vv = o & 31;
        Rout[b * 1024 + o] = (vv < uu) ? expf(R[uu][vv]) : 0.f;
    }
}

// ---- reshuffle (round-4 proven): octet j0 of bh b -> image writes ----
__device__ __forceinline__ void phase_reshuffle(
    const float* __restrict__ kptr,
    const float* __restrict__ vptr,
    const float* __restrict__ Rmat,
    uint4* __restrict__ kimg,
    uint4* __restrict__ vimg, int j0, int b, char* sm)
{
    float (*ls)[8][64] = (float(*)[8][64])sm;                  // 64 KB
    float (*lr)[33]    = (float(*)[33])(sm + 65536);           // 4.2 KB
    const int tid = threadIdx.x;
    const int w = tid >> 6, g = (tid >> 3) & 7, c8 = tid & 7;
    const int u = g * 4 + w;          // balanced bijection onto 0..31

    for (int o = tid; o < 1024; o += 256)
        lr[o >> 5][o & 31] = Rmat[b * 1024 + o];

    float4* ls4 = (float4*)ls;

    // ================= K phase =================
    {
        const float4* kb4 = (const float4*)kptr + (size_t)b * 65536 + j0 * 128;
        for (int it = 0; it < 16; ++it) {
            const int idx = it * 256 + tid;           // 4096 float4
            const int v = idx >> 7, i = idx & 127;    // i = row*16 + c4
            ls4[v * 128 + i] = kb4[v * 2048 + i];
        }
    }
    __syncthreads();
    {
        float ka[8][8];
        #pragma unroll
        for (int r = 0; r < 8; ++r)
            #pragma unroll
            for (int t = 0; t < 8; ++t) ka[r][t] = 0.f;
        for (int vv = 0; vv < u; ++vv) {
            const float rwt = lr[u][vv];
            #pragma unroll
            for (int r = 0; r < 8; ++r)
                #pragma unroll
                for (int t = 0; t < 8; ++t)
                    ka[r][t] = fmaf(rwt, ls[vv][r][c8 * 8 + t], ka[r][t]);
        }
        uint4* kdst = kimg + ((size_t)b * 32 + u) * 2048;
        #pragma unroll
        for (int r = 0; r < 8; ++r) {
            kdst[(j0 * 8 + r) * 8 + (c8 ^ r)] = packbf8(ka[r]);
            float o8[8];
            #pragma unroll
            for (int t = 0; t < 8; ++t) o8[t] = ls[u][r][c8 * 8 + t];
            kdst[(128 + j0 * 8 + r) * 8 + (c8 ^ r)] = packbf8(o8);
        }
    }
    __syncthreads();

    // ================= V phase =================
    {
        const float4* vb4 = (const float4*)vptr + (size_t)b * 65536 + j0 * 128;
        for (int it = 0; it < 16; ++it) {
            const int idx = it * 256 + tid;
            const int v = idx >> 7, i = idx & 127;
            ls4[v * 128 + i] = vb4[v * 2048 + i];
        }
    }
    __syncthreads();
    {
        // pack the original-bucket half from ls[u] first (reads ls)
        uint4 wor[8];
        #pragma unroll
        for (int t = 0; t < 8; ++t) {
            wor[t].x = f2bf(ls[u][0][c8 * 8 + t]) | (f2bf(ls[u][1][c8 * 8 + t]) << 16);
            wor[t].y = f2bf(ls[u][2][c8 * 8 + t]) | (f2bf(ls[u][3][c8 * 8 + t]) << 16);
            wor[t].z = f2bf(ls[u][4][c8 * 8 + t]) | (f2bf(ls[u][5][c8 * 8 + t]) << 16);
            wor[t].w = f2bf(ls[u][6][c8 * 8 + t]) | (f2bf(ls[u][7][c8 * 8 + t]) << 16);
        }
        // compute R·V for this octet (reads ls)
        float va[8][8];
        #pragma unroll
        for (int r = 0; r < 8; ++r)
            #pragma unroll
            for (int t = 0; t < 8; ++t) va[r][t] = 0.f;
        for (int vv = 0; vv < u; ++vv) {
            const float rwt = lr[u][vv];
            #pragma unroll
            for (int r = 0; r < 8; ++r)
                #pragma unroll
                for (int t = 0; t < 8; ++t)
                    va[r][t] = fmaf(rwt, ls[vv][r][c8 * 8 + t], va[r][t]);
        }
        __syncthreads();      // all ls reads done; reuse ls as image buffer

        // stage the panel image in LDS: [0,2048) = re, [2048,4096) = orig
        uint4* img = (uint4*)ls;
        #pragma unroll
        for (int t = 0; t < 8; ++t) {
            const int blk = c8 * 8 + (t ^ c8);        // d = c8*8+t
            uint4 wre;
            wre.x = f2bf(va[0][t]) | (f2bf(va[1][t]) << 16);
            wre.y = f2bf(va[2][t]) | (f2bf(va[3][t]) << 16);
            wre.z = f2bf(va[4][t]) | (f2bf(va[5][t]) << 16);
            wre.w = f2bf(va[6][t]) | (f2bf(va[7][t]) << 16);
            img[u * 64 + blk] = wre;
            img[2048 + u * 64 + blk] = wor[t];
        }
        __syncthreads();

        // linear, fully-coalesced image write (1 KB contiguous per bucket-panel)
        for (int o = tid; o < 2048; o += 256) {
            const int uu = o >> 6, blk = o & 63;
            const size_t tb = ((size_t)b * 32 + uu) * 2048;
            vimg[tb + j0 * 64 + blk] = img[o];
            vimg[tb + (16 + j0) * 64 + blk] = img[2048 + o];
        }
    }
}

// ---- MFMA attention for tile (b,u) (round-2 proven attn_mfma2) ----
__device__ __forceinline__ void phase_attn(
    const float* __restrict__ qptr,
    const uint4* __restrict__ kimg,
    const uint4* __restrict__ vimg,
    float* __restrict__ optr, int u, int b, char* sm)
{
    uint4* sK = (uint4*)sm;                // 32 KB
    uint4* sV = (uint4*)(sm + 32768);      // 32 KB
    uint4* sP = (uint4*)(sm + 65536);      // 16 KB
    const int tid = threadIdx.x;
    const int lane = tid & 63;
    const int w = tid >> 6;            // wave 0..3
    const int lg = lane >> 4;          // k-group 0..3
    const int lr = lane & 15;          // row/col-in-tile

    const size_t tile = (size_t)b * 32 + u;
    const uint4* gk = kimg + tile * 2048;
    const uint4* gv = vimg + tile * 2048;

    // ---- pure-DMA staging: image layouts already match LDS ----
    #pragma unroll
    for (int it = 0; it < 8; ++it)
        load_lds16(gk + it * 256 + tid, &sK[it * 256 + (w << 6)]);
    #pragma unroll
    for (int it = 0; it < 8; ++it)
        load_lds16(gv + it * 256 + tid, &sV[it * 256 + (w << 6)]);

    // ---- Q fragments direct from fp32 global (pre-scaled by 2^-5) ----
    const float* qbase = qptr + (size_t)b * 262144 + (size_t)u * 8192;
    bf16x8 qf[2][2];
    #pragma unroll
    for (int mt = 0; mt < 2; ++mt)
        #pragma unroll
        for (int c = 0; c < 2; ++c) {
            const int row = w * 32 + mt * 16 + lr;
            const float4* qr = (const float4*)(qbase + row * 64 + (c * 4 + lg) * 8);
            float4 a = qr[0], cc = qr[1];
            float f[8] = {a.x * SCALE, a.y * SCALE, a.z * SCALE, a.w * SCALE,
                          cc.x * SCALE, cc.y * SCALE, cc.z * SCALE, cc.w * SCALE};
            uint4 tq = packbf8(f);
            qf[mt][c] = *(bf16x8*)&tq;
        }
    __syncthreads();   // drains DMA (vmcnt) before any LDS read

    uint4* sPw = sP + w * 256;
    unsigned short* sPh = (unsigned short*)sPw;

    f32x4 acc[2][4];
    float lsum[2][4];
    #pragma unroll
    for (int mt = 0; mt < 2; ++mt) {
        #pragma unroll
        for (int nt = 0; nt < 4; ++nt) {
            acc[mt][nt][0] = 0.f; acc[mt][nt][1] = 0.f;
            acc[mt][nt][2] = 0.f; acc[mt][nt][3] = 0.f;
        }
        #pragma unroll
        for (int r = 0; r < 4; ++r) lsum[mt][r] = 0.f;
    }

    for (int kb = 0; kb < 4; ++kb) {
        // K B-fragments for this 64-key block
        bf16x8 kf[4][2];
        #pragma unroll
        for (int nt = 0; nt < 4; ++nt)
            #pragma unroll
            for (int c = 0; c < 2; ++c) {
                const int j = kb * 64 + nt * 16 + lr;
                const int dcu = c * 4 + lg;
                uint4 t = sK[j * 8 + (dcu ^ (j & 7))];
                kf[nt][c] = *(bf16x8*)&t;
            }
        // S = Q K^T  (D layout: col=key=lr, row=q=lg*4+reg)
        f32x4 s[2][4];
        #pragma unroll
        for (int mt = 0; mt < 2; ++mt)
            #pragma unroll
            for (int nt = 0; nt < 4; ++nt) {
                s[mt][nt][0] = 0.f; s[mt][nt][1] = 0.f;
                s[mt][nt][2] = 0.f; s[mt][nt][3] = 0.f;
            }
        __builtin_amdgcn_s_setprio(1);
        #pragma unroll
        for (int c = 0; c < 2; ++c)
            #pragma unroll
            for (int mt = 0; mt < 2; ++mt)
                #pragma unroll
                for (int nt = 0; nt < 4; ++nt)
                    s[mt][nt] = __builtin_amdgcn_mfma_f32_16x16x32_bf16(
                        qf[mt][c], kf[nt][c], s[mt][nt], 0, 0, 0);
        __builtin_amdgcn_s_setprio(0);

        // p = exp(s) (shift-free, logits O(1)); row-sums; P -> LDS (bf16)
        #pragma unroll
        for (int mt = 0; mt < 2; ++mt)
            #pragma unroll
            for (int nt = 0; nt < 4; ++nt)
                #pragma unroll
                for (int r = 0; r < 4; ++r) {
                    const float p = __expf(s[mt][nt][r]);
                    lsum[mt][r] += p;
                    const int row = mt * 16 + lg * 4 + r;     // 0..31
                    const int col = nt * 16 + lr;             // 0..63
                    sPh[row * 64 + (((col >> 3) ^ (row & 7)) << 3) + (col & 7)] =
                        (unsigned short)f2bf(p);
                }
        asm volatile("s_waitcnt lgkmcnt(0)" ::: "memory");
        __builtin_amdgcn_sched_barrier(0);

        // P A-fragments (row = lr, k = keys)
        bf16x8 pf[2][2];
        #pragma unroll
        for (int mt = 0; mt < 2; ++mt)
            #pragma unroll
            for (int c = 0; c < 2; ++c) {
                const int row = mt * 16 + lr;
                const int dcu = c * 4 + lg;
                uint4 t = sPw[row * 8 + (dcu ^ (row & 7))];
                pf[mt][c] = *(bf16x8*)&t;
            }
        // V B-fragments from panels (8 consecutive j at fixed d)
        bf16x8 vf[4][2];
        #pragma unroll
        for (int nt = 0; nt < 4; ++nt)
            #pragma unroll
            for (int c = 0; c < 2; ++c) {
                const int p = kb * 8 + c * 4 + lg;            // j>>3
                const int d = nt * 16 + lr;
                const int blk = (d >> 3) * 8 + ((d & 7) ^ ((d >> 3) & 7));
                uint4 t = sV[p * 64 + blk];
                vf[nt][c] = *(bf16x8*)&t;
            }
        // O += P V
        __builtin_amdgcn_s_setprio(1);
        #pragma unroll
        for (int c = 0; c < 2; ++c)
            #pragma unroll
            for (int mt = 0; mt < 2; ++mt)
                #pragma unroll
                for (int nt = 0; nt < 4; ++nt)
                    acc[mt][nt] = __builtin_amdgcn_mfma_f32_16x16x32_bf16(
                        pf[mt][c], vf[nt][c], acc[mt][nt], 0, 0, 0);
        __builtin_amdgcn_s_setprio(0);
    }

    // ---- normalize and store (fp32) ----
    #pragma unroll
    for (int mt = 0; mt < 2; ++mt)
        #pragma unroll
        for (int r = 0; r < 4; ++r) {
            float sum = lsum[mt][r];
            sum += __shfl_xor(sum, 1);
            sum += __shfl_xor(sum, 2);
            sum += __shfl_xor(sum, 4);
            sum += __shfl_xor(sum, 8);
            const float inv = 1.f / sum;
            const int row = mt * 16 + lg * 4 + r;
            float* orow = optr + (size_t)b * 262144 +
                          (size_t)(u * 128 + w * 32 + row) * 64;
            #pragma unroll
            for (int nt = 0; nt < 4; ++nt)
                orow[nt * 16 + lr] = acc[mt][nt][r] * inv;
        }
}

// ============================================================
// Cooperative mega-kernel: 512 blocks x 256 thr, 80 KB LDS
// (2 blocks/CU — same residency attn_mfma2 already proves).
// ============================================================
__global__ __launch_bounds__(256, 2) void mega_kernel(
    const float* __restrict__ q,
    const float* __restrict__ k,
    const float* __restrict__ v,
    const float* __restrict__ swp,
    const float* __restrict__ gp,
    float* __restrict__ R,
    float* __restrict__ bkr,
    uint4* __restrict__ kimg,
    uint4* __restrict__ vimg,
    float* __restrict__ out)
{
    __shared__ __align__(16) char sm[81920];
    cg::grid_group grid = cg::this_grid();
    const int blk = blockIdx.x;

    // Phase 1a: bucket sums (2048 vblocks)
    #pragma unroll 1
    for (int rep = 0; rep < 4; ++rep)
        phase_bksum(k, bkr, blk * 4 + rep, sm);
    grid.sync();

    // Phase 1b: Sinkhorn (64 vblocks)
    if (blk < 64) phase_sink(bkr, swp, gp, R, blk, sm);
    grid.sync();

    // Phase 2: reshuffle (1024 vblocks)
    #pragma unroll 1
    for (int rep = 0; rep < 2; ++rep) {
        __syncthreads();
        const int vb = blk * 2 + rep;
        phase_reshuffle(k, v, R, kimg, vimg, vb & 15, vb >> 4, sm);
    }
    grid.sync();

    // Phase 3: attention (2048 vblocks)
    #pragma unroll 1
    for (int rep = 0; rep < 4; ++rep) {
        __syncthreads();
        const int vb = blk * 4 + rep;
        phase_attn(q, kimg, vimg, out, vb & 31, vb >> 5, sm);
    }
}

// ============================================================
// Standalone kernels (fallback path if cooperative launch fails)
// ============================================================
__global__ __launch_bounds__(256) void bksum_k(
    const float* __restrict__ kptr, float* __restrict__ bkr)
{
    __shared__ __align__(16) char sm[4352];
    phase_bksum(kptr, bkr, blockIdx.x, sm);
}

__global__ __launch_bounds__(256) void sink_k(
    const float* __restrict__ bkrp,
    const float* __restrict__ swptr,
    const float* __restrict__ gptr,
    float* __restrict__ Rout)
{
    __shared__ __align__(16) char sm[20608];
    phase_sink(bkrp, swptr, gptr, Rout, blockIdx.x, sm);
}

__global__ __launch_bounds__(256) void reshuffle_k(
    const float* __restrict__ kptr,
    const float* __restrict__ vptr,
    const float* __restrict__ Rmat,
    uint4* __restrict__ kimg,
    uint4* __restrict__ vimg)
{
    __shared__ __align__(16) char sm[69760];
    phase_reshuffle(kptr, vptr, Rmat, kimg, vimg, blockIdx.x, blockIdx.y, sm);
}

__global__ __launch_bounds__(256) void attn_k(
    const float* __restrict__ qptr,
    const uint4* __restrict__ kimg,
    const uint4* __restrict__ vimg,
    float* __restrict__ optr)
{
    __shared__ __align__(16) char sm[81920];
    phase_attn(qptr, kimg, vimg, optr, blockIdx.x, blockIdx.y, sm);
}

// ============================================================
// Fallback (small ws): per-(bh,bucket) VALU attention
// ============================================================
__global__ __launch_bounds__(128) void attn_fallback(
    const float* __restrict__ qptr,
    const float* __restrict__ kptr,
    const float* __restrict__ vptr,
    const float* __restrict__ Rmat,
    float4* __restrict__ optr)
{
    const int u = blockIdx.x;
    const int b = blockIdx.y;
    const int tid = threadIdx.x;

    __shared__ uint4 sbk[2048];
    __shared__ uint4 sbv[2048];

    const float4* k4 = (const float4*)kptr + (size_t)b * 65536;
    const float4* v4 = (const float4*)vptr + (size_t)b * 65536;
    const float4* q4 = (const float4*)qptr + (size_t)b * 65536;

    const float* Rrow = Rmat + (b * BUCKETS + u) * BUCKETS;
    for (int o = tid; o < 1024; o += 128) {
        float ka[8] = {0.f,0.f,0.f,0.f,0.f,0.f,0.f,0.f};
        float va[8] = {0.f,0.f,0.f,0.f,0.f,0.f,0.f,0.f};
        for (int vv = 0; vv < u; ++vv) {
            const float r = Rrow[vv];
            float4 a = k4[vv * 2048 + 2 * o], c = k4[vv * 2048 + 2 * o + 1];
            ka[0] = fmaf(r, a.x, ka[0]); ka[1] = fmaf(r, a.y, ka[1]);
            ka[2] = fmaf(r, a.z, ka[2]); ka[3] = fmaf(r, a.w, ka[3]);
            ka[4] = fmaf(r, c.x, ka[4]); ka[5] = fmaf(r, c.y, ka[5]);
            ka[6] = fmaf(r, c.z, ka[6]); ka[7] = fmaf(r, c.w, ka[7]);
            float4 av = v4[vv * 2048 + 2 * o], cv = v4[vv * 2048 + 2 * o + 1];
            va[0] = fmaf(r, av.x, va[0]); va[1] = fmaf(r, av.y, va[1]);
            va[2] = fmaf(r, av.z, va[2]); va[3] = fmaf(r, av.w, va[3]);
            va[4] = fmaf(r, cv.x, va[4]); va[5] = fmaf(r, cv.y, va[5]);
            va[6] = fmaf(r, cv.z, va[6]); va[7] = fmaf(r, cv.w, va[7]);
        }
        sbk[o] = packbf8(ka);
        sbv[o] = packbf8(va);
        float4 a = k4[u * 2048 + 2 * o], c = k4[u * 2048 + 2 * o + 1];
        float f[8] = {a.x,a.y,a.z,a.w,c.x,c.y,c.z,c.w};
        sbk[1024 + o] = packbf8(f);
        float4 av = v4[u * 2048 + 2 * o], cv = v4[u * 2048 + 2 * o + 1];
        float gg[8] = {av.x,av.y,av.z,av.w,cv.x,cv.y,cv.z,cv.w};
        sbv[1024 + o] = packbf8(gg);
    }
    __syncthreads();

    const int i = tid;
    float qr[64];
    const float4* qrow = q4 + (u * 128 + i) * 16;
    for (int d4 = 0; d4 < 16; ++d4) {
        float4 t = qrow[d4];
        qr[d4 * 4 + 0] = t.x; qr[d4 * 4 + 1] = t.y;
        qr[d4 * 4 + 2] = t.z; qr[d4 * 4 + 3] = t.w;
    }

    float acc[64];
    for (int d = 0; d < 64; ++d) acc[d] = 0.f;
    float l = 0.f;

    for (int j = 0; j < 256; ++j) {
        float s = 0.f;
        for (int d8 = 0; d8 < 8; ++d8) {
            float f[8];
            bf8_to_f32(sbk[j * 8 + d8], f);
            for (int t = 0; t < 8; ++t) s = fmaf(qr[d8 * 8 + t], f[t], s);
        }
        const float p = __expf(s * SCALE);
        l += p;
        for (int d8 = 0; d8 < 8; ++d8) {
            float f[8];
            bf8_to_f32(sbv[j * 8 + d8], f);
            for (int t = 0; t < 8; ++t)
                acc[d8 * 8 + t] = fmaf(p, f[t], acc[d8 * 8 + t]);
        }
    }

    const float inv = 1.f / l;
    float4* orow = optr + (size_t)b * 65536 + (u * 128 + i) * 16;
    for (int d4 = 0; d4 < 16; ++d4) {
        float4 t;
        t.x = acc[d4 * 4 + 0] * inv;
        t.y = acc[d4 * 4 + 1] * inv;
        t.z = acc[d4 * 4 + 2] * inv;
        t.w = acc[d4 * 4 + 3] * inv;
        orow[d4] = t;
    }
}

extern "C" void kernel_launch(void* const* d_in, const int* in_sizes, int n_in,
                              void* d_out, int out_size, void* d_ws, size_t ws_size,
                              hipStream_t stream) {
    const float* q  = (const float*)d_in[0];
    const float* k  = (const float*)d_in[1];
    const float* v  = (const float*)d_in[2];
    const float* sw = (const float*)d_in[3];
    const float* g  = (const float*)d_in[4];
    float* out = (float*)d_out;

    // ws layout: R fp32 (256 KB) | bkr fp32 (512 KB) | pad to 1 MB |
    //            kimg bf16 image (67.1 MB) | vimg bf16 image (67.1 MB)
    float* R    = (float*)d_ws;
    float* bkr  = (float*)((char*)d_ws + 262144);
    uint4* kimg = (uint4*)((char*)d_ws + 1048576);
    uint4* vimg = (uint4*)((char*)d_ws + 1048576 + 67108864);
    const bool big_ws = (ws_size >= (size_t)1048576 + 2u * 67108864u);

    if (big_ws) {
        void* args[] = {(void*)&q, (void*)&k, (void*)&v, (void*)&sw, (void*)&g,
                        (void*)&R, (void*)&bkr, (void*)&kimg, (void*)&vimg, (void*)&out};
        hipError_t e = hipLaunchCooperativeKernel(
            (const void*)mega_kernel, dim3(512), dim3(256), args, 0, stream);
        if (e != hipSuccess) {
            // fallback: proven 4-kernel pipeline
            bksum_k<<<dim3(2048), dim3(256), 0, stream>>>(k, bkr);
            sink_k<<<dim3(64), dim3(256), 0, stream>>>(bkr, sw, g, R);
            reshuffle_k<<<dim3(16, 64), dim3(256), 0, stream>>>(k, v, R, kimg, vimg);
            attn_k<<<dim3(32, 64), dim3(256), 0, stream>>>(q, kimg, vimg, out);
        }
    } else {
        bksum_k<<<dim3(2048), dim3(256), 0, stream>>>(k, bkr);
        sink_k<<<dim3(64), dim3(256), 0, stream>>>(bkr, sw, g, R);
        attn_fallback<<<dim3(32, 64), dim3(128), 0, stream>>>(q, k, v, R, (float4*)d_out);
    }
}

// Round 7
// 327.716 us; speedup vs baseline: 1.5411x; 1.5411x over previous
//
#include <hip/hip_runtime.h>
#include <hip/hip_bf16.h>

#define BUCKETS 32
#define BSZ 128            // tokens per bucket (4096/32)
#define DH 64
#define TEMPINV 1.3333333333333333f   // 1/0.75
#define SINK_ITERS 7
#define LOG_EPS 1e-6f
#define SCALE 0.03125f     // DIM^-0.5 = 1024^-0.5

typedef short bf16x8 __attribute__((ext_vector_type(8)));   // 8 bf16 in 4 VGPRs
typedef float f32x4 __attribute__((ext_vector_type(4)));

// ---- bf16 helpers (bit-level, RNE rounding) ----
__device__ __forceinline__ void bf8_to_f32(const uint4 x, float* f) {
    f[0] = __uint_as_float(x.x << 16);
    f[1] = __uint_as_float(x.x & 0xffff0000u);
    f[2] = __uint_as_float(x.y << 16);
    f[3] = __uint_as_float(x.y & 0xffff0000u);
    f[4] = __uint_as_float(x.z << 16);
    f[5] = __uint_as_float(x.z & 0xffff0000u);
    f[6] = __uint_as_float(x.w << 16);
    f[7] = __uint_as_float(x.w & 0xffff0000u);
}

__device__ __forceinline__ unsigned f2bf(float f) {
    unsigned x = __float_as_uint(f);
    return (x + 0x7fffu + ((x >> 16) & 1u)) >> 16;   // RNE (no NaN in this data)
}

__device__ __forceinline__ uint4 packbf8(const float* f) {
    uint4 r;
    r.x = f2bf(f[0]) | (f2bf(f[1]) << 16);
    r.y = f2bf(f[2]) | (f2bf(f[3]) << 16);
    r.z = f2bf(f[4]) | (f2bf(f[5]) << 16);
    r.w = f2bf(f[6]) | (f2bf(f[7]) << 16);
    return r;
}

// async global->LDS DMA, 16 B per lane; dest is wave-uniform base + lane*16
__device__ __forceinline__ void load_lds16(const uint4* g, uint4* l) {
    __builtin_amdgcn_global_load_lds(
        (const __attribute__((address_space(1))) unsigned int*)g,
        (__attribute__((address_space(3))) unsigned int*)l, 16, 0, 0);
}

// ============================================================
// Kernel 1: sink_fused — bucket-K sums + logits + Sinkhorn -> R
//   grid 64 (one per bh), 1024 threads (16 waves). (round-5 proven)
//   bkr kept in LDS (no HBM round-trip); K[b] read once (1 MB);
//   also warms L3 with K ahead of reshuffle.
// ============================================================
__global__ __launch_bounds__(1024) void sink_fused(
    const float* __restrict__ kptr,
    const float* __restrict__ swptr,
    const float* __restrict__ gptr,
    float* __restrict__ Rout)
{
    const int b = blockIdx.x;
    const int h = b & 15;
    const int tid = threadIdx.x;

    __shared__ float bk[BUCKETS][DH];         // 8 KB
    __shared__ float swl[DH][BUCKETS];        // 8 KB
    __shared__ float R[BUCKETS][BUCKETS + 1];

    // bucket sums: thread (u = tid>>5, dp = tid&31) owns 2 d-columns
    {
        const int u = tid >> 5, dp = tid & 31;
        const float2* base = (const float2*)kptr + ((size_t)b * 32 + u) * 4096 + dp;
        float sx = 0.f, sy = 0.f;
        for (int t = 0; t < BSZ; ++t) {
            const float2 a = base[t * 32];
            sx += a.x; sy += a.y;
        }
        bk[u][dp * 2] = sx;
        bk[u][dp * 2 + 1] = sy;
    }
    // stage sort_w[h] (layout h,d,v)
    for (int o = tid; o < DH * BUCKETS; o += 1024)
        swl[o >> 5][o & 31] = swptr[h * DH * BUCKETS + o];
    __syncthreads();

    // logits: one entry per thread
    {
        const int uu = tid >> 5, vv = tid & 31;
        float dot = 0.f;
        for (int d = 0; d < DH; ++d) dot = fmaf(bk[uu][d], swl[d][vv], dot);
        R[uu][vv] = (logf(fmaxf(dot, 0.f) + LOG_EPS) + gptr[b * 1024 + tid]) * TEMPINV;
    }
    __syncthreads();

    // Sinkhorn (threads 0..255 active; 8 lanes per row/col)
    const int rr = tid >> 3, sub = tid & 7;
    for (int it = 0; it < SINK_ITERS; ++it) {
        if (tid < 256) {
            float vals[4];
            float m = -1e30f, s = 0.f;
            #pragma unroll
            for (int q = 0; q < 4; ++q) { vals[q] = R[rr][sub * 4 + q]; m = fmaxf(m, vals[q]); }
            m = fmaxf(m, __shfl_xor(m, 1)); m = fmaxf(m, __shfl_xor(m, 2)); m = fmaxf(m, __shfl_xor(m, 4));
            #pragma unroll
            for (int q = 0; q < 4; ++q) s += expf(vals[q] - m);
            s += __shfl_xor(s, 1); s += __shfl_xor(s, 2); s += __shfl_xor(s, 4);
            const float lse = m + logf(s);
            #pragma unroll
            for (int q = 0; q < 4; ++q) R[rr][sub * 4 + q] = vals[q] - lse;
        }
        __syncthreads();
        if (tid < 256) {
            float vals[4];
            float m = -1e30f, s = 0.f;
            #pragma unroll
            for (int q = 0; q < 4; ++q) { vals[q] = R[sub * 4 + q][rr]; m = fmaxf(m, vals[q]); }
            m = fmaxf(m, __shfl_xor(m, 1)); m = fmaxf(m, __shfl_xor(m, 2)); m = fmaxf(m, __shfl_xor(m, 4));
            #pragma unroll
            for (int q = 0; q < 4; ++q) s += expf(vals[q] - m);
            s += __shfl_xor(s, 1); s += __shfl_xor(s, 2); s += __shfl_xor(s, 4);
            const float lse = m + logf(s);
            #pragma unroll
            for (int q = 0; q < 4; ++q) R[sub * 4 + q][rr] = vals[q] - lse;
        }
        __syncthreads();
    }

    {
        const int uu = tid >> 5, vv = tid & 31;
        Rout[b * 1024 + tid] = (vv < uu) ? expf(R[uu][vv]) : 0.f;
    }
}

// ============================================================
// Kernel 2: reshuffle4 — pre-swizzled bf16 image writes (round-4 proven).
//   grid (16 row-octets, 64 bh), 256 threads, LDS 68 KB (2 blocks/CU).
//   Wave-balanced bucket map u = g*4 + w; V image routed through LDS
//   and written with linear coalesced uint4 stores.
// ============================================================
__global__ __launch_bounds__(256) void reshuffle4_kernel(
    const float* __restrict__ kptr,
    const float* __restrict__ vptr,
    const float* __restrict__ Rmat,
    uint4* __restrict__ kimg,
    uint4* __restrict__ vimg)
{
    const int j0 = blockIdx.x;        // token rows 8j0..8j0+7
    const int b  = blockIdx.y;
    const int tid = threadIdx.x;
    const int w = tid >> 6, g = (tid >> 3) & 7, c8 = tid & 7;
    const int u = g * 4 + w;          // balanced bijection onto 0..31

    __shared__ float ls[32][8][64];   // 64 KB: [bucket][row-in-octet][d]
    __shared__ float lr[32][33];

    for (int o = tid; o < 1024; o += 256)
        lr[o >> 5][o & 31] = Rmat[b * 1024 + o];

    float4* ls4 = (float4*)ls;

    // ================= K phase =================
    {
        const float4* kb4 = (const float4*)kptr + (size_t)b * 65536 + j0 * 128;
        for (int it = 0; it < 16; ++it) {
            const int idx = it * 256 + tid;           // 4096 float4
            const int v = idx >> 7, i = idx & 127;    // i = row*16 + c4
            ls4[v * 128 + i] = kb4[v * 2048 + i];
        }
    }
    __syncthreads();
    {
        float ka[8][8];
        #pragma unroll
        for (int r = 0; r < 8; ++r)
            #pragma unroll
            for (int t = 0; t < 8; ++t) ka[r][t] = 0.f;
        for (int vv = 0; vv < u; ++vv) {
            const float rwt = lr[u][vv];
            #pragma unroll
            for (int r = 0; r < 8; ++r)
                #pragma unroll
                for (int t = 0; t < 8; ++t)
                    ka[r][t] = fmaf(rwt, ls[vv][r][c8 * 8 + t], ka[r][t]);
        }
        uint4* kdst = kimg + ((size_t)b * 32 + u) * 2048;
        #pragma unroll
        for (int r = 0; r < 8; ++r) {
            kdst[(j0 * 8 + r) * 8 + (c8 ^ r)] = packbf8(ka[r]);
            float o8[8];
            #pragma unroll
            for (int t = 0; t < 8; ++t) o8[t] = ls[u][r][c8 * 8 + t];
            kdst[(128 + j0 * 8 + r) * 8 + (c8 ^ r)] = packbf8(o8);
        }
    }
    __syncthreads();

    // ================= V phase =================
    {
        const float4* vb4 = (const float4*)vptr + (size_t)b * 65536 + j0 * 128;
        for (int it = 0; it < 16; ++it) {
            const int idx = it * 256 + tid;
            const int v = idx >> 7, i = idx & 127;
            ls4[v * 128 + i] = vb4[v * 2048 + i];
        }
    }
    __syncthreads();
    {
        // pack the original-bucket half from ls[u] first (reads ls)
        uint4 wor[8];
        #pragma unroll
        for (int t = 0; t < 8; ++t) {
            wor[t].x = f2bf(ls[u][0][c8 * 8 + t]) | (f2bf(ls[u][1][c8 * 8 + t]) << 16);
            wor[t].y = f2bf(ls[u][2][c8 * 8 + t]) | (f2bf(ls[u][3][c8 * 8 + t]) << 16);
            wor[t].z = f2bf(ls[u][4][c8 * 8 + t]) | (f2bf(ls[u][5][c8 * 8 + t]) << 16);
            wor[t].w = f2bf(ls[u][6][c8 * 8 + t]) | (f2bf(ls[u][7][c8 * 8 + t]) << 16);
        }
        // compute R·V for this octet (reads ls)
        float va[8][8];
        #pragma unroll
        for (int r = 0; r < 8; ++r)
            #pragma unroll
            for (int t = 0; t < 8; ++t) va[r][t] = 0.f;
        for (int vv = 0; vv < u; ++vv) {
            const float rwt = lr[u][vv];
            #pragma unroll
            for (int r = 0; r < 8; ++r)
                #pragma unroll
                for (int t = 0; t < 8; ++t)
                    va[r][t] = fmaf(rwt, ls[vv][r][c8 * 8 + t], va[r][t]);
        }
        __syncthreads();      // all ls reads done; reuse ls as image buffer

        // stage the panel image in LDS: [0,2048) = re, [2048,4096) = orig
        uint4* img = (uint4*)ls;
        #pragma unroll
        for (int t = 0; t < 8; ++t) {
            const int blk = c8 * 8 + (t ^ c8);        // d = c8*8+t
            uint4 wre;
            wre.x = f2bf(va[0][t]) | (f2bf(va[1][t]) << 16);
            wre.y = f2bf(va[2][t]) | (f2bf(va[3][t]) << 16);
            wre.z = f2bf(va[4][t]) | (f2bf(va[5][t]) << 16);
            wre.w = f2bf(va[6][t]) | (f2bf(va[7][t]) << 16);
            img[u * 64 + blk] = wre;
            img[2048 + u * 64 + blk] = wor[t];
        }
        __syncthreads();

        // linear, fully-coalesced image write (1 KB contiguous per bucket-panel)
        for (int o = tid; o < 2048; o += 256) {
            const int uu = o >> 6, blk = o & 63;
            const size_t tb = ((size_t)b * 32 + uu) * 2048;
            vimg[tb + j0 * 64 + blk] = img[o];
            vimg[tb + (16 + j0) * 64 + blk] = img[2048 + o];
        }
    }
}

// ============================================================
// Kernel 3 (fallback, small ws): per-(bh,bucket) VALU attention
// ============================================================
__global__ __launch_bounds__(128) void attn_fallback(
    const float* __restrict__ qptr,
    const float* __restrict__ kptr,
    const float* __restrict__ vptr,
    const float* __restrict__ Rmat,
    float4* __restrict__ optr)
{
    const int u = blockIdx.x;
    const int b = blockIdx.y;
    const int tid = threadIdx.x;

    __shared__ uint4 sbk[2048];
    __shared__ uint4 sbv[2048];

    const float4* k4 = (const float4*)kptr + (size_t)b * 65536;
    const float4* v4 = (const float4*)vptr + (size_t)b * 65536;
    const float4* q4 = (const float4*)qptr + (size_t)b * 65536;

    const float* Rrow = Rmat + (b * BUCKETS + u) * BUCKETS;
    for (int o = tid; o < 1024; o += 128) {
        float ka[8] = {0.f,0.f,0.f,0.f,0.f,0.f,0.f,0.f};
        float va[8] = {0.f,0.f,0.f,0.f,0.f,0.f,0.f,0.f};
        for (int vv = 0; vv < u; ++vv) {
            const float r = Rrow[vv];
            float4 a = k4[vv * 2048 + 2 * o], c = k4[vv * 2048 + 2 * o + 1];
            ka[0] = fmaf(r, a.x, ka[0]); ka[1] = fmaf(r, a.y, ka[1]);
            ka[2] = fmaf(r, a.z, ka[2]); ka[3] = fmaf(r, a.w, ka[3]);
            ka[4] = fmaf(r, c.x, ka[4]); ka[5] = fmaf(r, c.y, ka[5]);
            ka[6] = fmaf(r, c.z, ka[6]); ka[7] = fmaf(r, c.w, ka[7]);
            float4 av = v4[vv * 2048 + 2 * o], cv = v4[vv * 2048 + 2 * o + 1];
            va[0] = fmaf(r, av.x, va[0]); va[1] = fmaf(r, av.y, va[1]);
            va[2] = fmaf(r, av.z, va[2]); va[3] = fmaf(r, av.w, va[3]);
            va[4] = fmaf(r, cv.x, va[4]); va[5] = fmaf(r, cv.y, va[5]);
            va[6] = fmaf(r, cv.z, va[6]); va[7] = fmaf(r, cv.w, va[7]);
        }
        sbk[o] = packbf8(ka);
        sbv[o] = packbf8(va);
        float4 a = k4[u * 2048 + 2 * o], c = k4[u * 2048 + 2 * o + 1];
        float f[8] = {a.x,a.y,a.z,a.w,c.x,c.y,c.z,c.w};
        sbk[1024 + o] = packbf8(f);
        float4 av = v4[u * 2048 + 2 * o], cv = v4[u * 2048 + 2 * o + 1];
        float gg[8] = {av.x,av.y,av.z,av.w,cv.x,cv.y,cv.z,cv.w};
        sbv[1024 + o] = packbf8(gg);
    }
    __syncthreads();

    const int i = tid;
    float qr[64];
    const float4* qrow = q4 + (u * 128 + i) * 16;
    for (int d4 = 0; d4 < 16; ++d4) {
        float4 t = qrow[d4];
        qr[d4 * 4 + 0] = t.x; qr[d4 * 4 + 1] = t.y;
        qr[d4 * 4 + 2] = t.z; qr[d4 * 4 + 3] = t.w;
    }

    float acc[64];
    for (int d = 0; d < 64; ++d) acc[d] = 0.f;
    float l = 0.f;

    for (int j = 0; j < 256; ++j) {
        float s = 0.f;
        for (int d8 = 0; d8 < 8; ++d8) {
            float f[8];
            bf8_to_f32(sbk[j * 8 + d8], f);
            for (int t = 0; t < 8; ++t) s = fmaf(qr[d8 * 8 + t], f[t], s);
        }
        const float p = __expf(s * SCALE);
        l += p;
        for (int d8 = 0; d8 < 8; ++d8) {
            float f[8];
            bf8_to_f32(sbv[j * 8 + d8], f);
            for (int t = 0; t < 8; ++t)
                acc[d8 * 8 + t] = fmaf(p, f[t], acc[d8 * 8 + t]);
        }
    }

    const float inv = 1.f / l;
    float4* orow = optr + (size_t)b * 65536 + (u * 128 + i) * 16;
    for (int d4 = 0; d4 < 16; ++d4) {
        float4 t;
        t.x = acc[d4 * 4 + 0] * inv;
        t.y = acc[d4 * 4 + 1] * inv;
        t.z = acc[d4 * 4 + 2] * inv;
        t.w = acc[d4 * 4 + 3] * inv;
        orow[d4] = t;
    }
}

// ============================================================
// Kernel 3 (main): MFMA attention, DMA-staged images (round-2 proven).
//   grid (32,64), 256 thr (4 waves); wave w owns q-rows [w*32, w*32+32)
// ============================================================
__global__ __launch_bounds__(256) void attn_mfma2(
    const float* __restrict__ qptr,
    const uint4* __restrict__ kimg,
    const uint4* __restrict__ vimg,
    float* __restrict__ optr)
{
    const int u = blockIdx.x;
    const int b = blockIdx.y;
    const int tid = threadIdx.x;
    const int lane = tid & 63;
    const int w = tid >> 6;            // wave 0..3
    const int lg = lane >> 4;          // k-group 0..3
    const int lr = lane & 15;          // row/col-in-tile

    __shared__ uint4 sK[2048];         // 32 KB
    __shared__ uint4 sV[2048];         // 32 KB
    __shared__ uint4 sP[1024];         // 16 KB (4 KB per wave)

    const size_t tile = (size_t)b * 32 + u;
    const uint4* gk = kimg + tile * 2048;
    const uint4* gv = vimg + tile * 2048;

    // ---- pure-DMA staging: image layouts already match LDS ----
    #pragma unroll
    for (int it = 0; it < 8; ++it)
        load_lds16(gk + it * 256 + tid, &sK[it * 256 + (w << 6)]);
    #pragma unroll
    for (int it = 0; it < 8; ++it)
        load_lds16(gv + it * 256 + tid, &sV[it * 256 + (w << 6)]);

    // ---- Q fragments direct from fp32 global (pre-scaled by 2^-5) ----
    const float* qbase = qptr + (size_t)b * 262144 + (size_t)u * 8192;
    bf16x8 qf[2][2];
    #pragma unroll
    for (int mt = 0; mt < 2; ++mt)
        #pragma unroll
        for (int c = 0; c < 2; ++c) {
            const int row = w * 32 + mt * 16 + lr;
            const float4* qr = (const float4*)(qbase + row * 64 + (c * 4 + lg) * 8);
            float4 a = qr[0], cc = qr[1];
            float f[8] = {a.x * SCALE, a.y * SCALE, a.z * SCALE, a.w * SCALE,
                          cc.x * SCALE, cc.y * SCALE, cc.z * SCALE, cc.w * SCALE};
            uint4 tq = packbf8(f);
            qf[mt][c] = *(bf16x8*)&tq;
        }
    __syncthreads();   // drains DMA (vmcnt) before any LDS read

    uint4* sPw = sP + w * 256;
    unsigned short* sPh = (unsigned short*)sPw;

    f32x4 acc[2][4];
    float lsum[2][4];
    #pragma unroll
    for (int mt = 0; mt < 2; ++mt) {
        #pragma unroll
        for (int nt = 0; nt < 4; ++nt) {
            acc[mt][nt][0] = 0.f; acc[mt][nt][1] = 0.f;
            acc[mt][nt][2] = 0.f; acc[mt][nt][3] = 0.f;
        }
        #pragma unroll
        for (int r = 0; r < 4; ++r) lsum[mt][r] = 0.f;
    }

    for (int kb = 0; kb < 4; ++kb) {
        // K B-fragments for this 64-key block
        bf16x8 kf[4][2];
        #pragma unroll
        for (int nt = 0; nt < 4; ++nt)
            #pragma unroll
            for (int c = 0; c < 2; ++c) {
                const int j = kb * 64 + nt * 16 + lr;
                const int dcu = c * 4 + lg;
                uint4 t = sK[j * 8 + (dcu ^ (j & 7))];
                kf[nt][c] = *(bf16x8*)&t;
            }
        // S = Q K^T  (D layout: col=key=lr, row=q=lg*4+reg)
        f32x4 s[2][4];
        #pragma unroll
        for (int mt = 0; mt < 2; ++mt)
            #pragma unroll
            for (int nt = 0; nt < 4; ++nt) {
                s[mt][nt][0] = 0.f; s[mt][nt][1] = 0.f;
                s[mt][nt][2] = 0.f; s[mt][nt][3] = 0.f;
            }
        __builtin_amdgcn_s_setprio(1);
        #pragma unroll
        for (int c = 0; c < 2; ++c)
            #pragma unroll
            for (int mt = 0; mt < 2; ++mt)
                #pragma unroll
                for (int nt = 0; nt < 4; ++nt)
                    s[mt][nt] = __builtin_amdgcn_mfma_f32_16x16x32_bf16(
                        qf[mt][c], kf[nt][c], s[mt][nt], 0, 0, 0);
        __builtin_amdgcn_s_setprio(0);

        // p = exp(s) (shift-free, logits O(1)); row-sums; P -> LDS (bf16)
        #pragma unroll
        for (int mt = 0; mt < 2; ++mt)
            #pragma unroll
            for (int nt = 0; nt < 4; ++nt)
                #pragma unroll
                for (int r = 0; r < 4; ++r) {
                    const float p = __expf(s[mt][nt][r]);
                    lsum[mt][r] += p;
                    const int row = mt * 16 + lg * 4 + r;     // 0..31
                    const int col = nt * 16 + lr;             // 0..63
                    sPh[row * 64 + (((col >> 3) ^ (row & 7)) << 3) + (col & 7)] =
                        (unsigned short)f2bf(p);
                }
        asm volatile("s_waitcnt lgkmcnt(0)" ::: "memory");
        __builtin_amdgcn_sched_barrier(0);

        // P A-fragments (row = lr, k = keys)
        bf16x8 pf[2][2];
        #pragma unroll
        for (int mt = 0; mt < 2; ++mt)
            #pragma unroll
            for (int c = 0; c < 2; ++c) {
                const int row = mt * 16 + lr;
                const int dcu = c * 4 + lg;
                uint4 t = sPw[row * 8 + (dcu ^ (row & 7))];
                pf[mt][c] = *(bf16x8*)&t;
            }
        // V B-fragments from panels (8 consecutive j at fixed d)
        bf16x8 vf[4][2];
        #pragma unroll
        for (int nt = 0; nt < 4; ++nt)
            #pragma unroll
            for (int c = 0; c < 2; ++c) {
                const int p = kb * 8 + c * 4 + lg;            // j>>3
                const int d = nt * 16 + lr;
                const int blk = (d >> 3) * 8 + ((d & 7) ^ ((d >> 3) & 7));
                uint4 t = sV[p * 64 + blk];
                vf[nt][c] = *(bf16x8*)&t;
            }
        // O += P V
        __builtin_amdgcn_s_setprio(1);
        #pragma unroll
        for (int c = 0; c < 2; ++c)
            #pragma unroll
            for (int mt = 0; mt < 2; ++mt)
                #pragma unroll
                for (int nt = 0; nt < 4; ++nt)
                    acc[mt][nt] = __builtin_amdgcn_mfma_f32_16x16x32_bf16(
                        pf[mt][c], vf[nt][c], acc[mt][nt], 0, 0, 0);
        __builtin_amdgcn_s_setprio(0);
    }

    // ---- normalize and store (fp32) ----
    #pragma unroll
    for (int mt = 0; mt < 2; ++mt)
        #pragma unroll
        for (int r = 0; r < 4; ++r) {
            float sum = lsum[mt][r];
            sum += __shfl_xor(sum, 1);
            sum += __shfl_xor(sum, 2);
            sum += __shfl_xor(sum, 4);
            sum += __shfl_xor(sum, 8);
            const float inv = 1.f / sum;
            const int row = mt * 16 + lg * 4 + r;
            float* orow = optr + (size_t)b * 262144 +
                          (size_t)(u * 128 + w * 32 + row) * 64;
            #pragma unroll
            for (int nt = 0; nt < 4; ++nt)
                orow[nt * 16 + lr] = acc[mt][nt][r] * inv;
        }
}

extern "C" void kernel_launch(void* const* d_in, const int* in_sizes, int n_in,
                              void* d_out, int out_size, void* d_ws, size_t ws_size,
                              hipStream_t stream) {
    const float* q  = (const float*)d_in[0];
    const float* k  = (const float*)d_in[1];
    const float* v  = (const float*)d_in[2];
    const float* sw = (const float*)d_in[3];
    const float* g  = (const float*)d_in[4];

    // ws layout: R fp32 (256 KB) | pad to 1 MB |
    //            kimg bf16 image (67.1 MB) | vimg bf16 image (67.1 MB)
    float* R    = (float*)d_ws;
    uint4* kimg = (uint4*)((char*)d_ws + 1048576);
    uint4* vimg = (uint4*)((char*)d_ws + 1048576 + 67108864);
    const bool big_ws = (ws_size >= (size_t)1048576 + 2u * 67108864u);

    sink_fused<<<dim3(64), dim3(1024), 0, stream>>>(k, sw, g, R);
    if (big_ws) {
        reshuffle4_kernel<<<dim3(16, 64), dim3(256), 0, stream>>>(k, v, R, kimg, vimg);
        attn_mfma2<<<dim3(32, 64), dim3(256), 0, stream>>>(q, kimg, vimg, (float*)d_out);
    } else {
        attn_fallback<<<dim3(32, 64), dim3(128), 0, stream>>>(q, k, v, R, (float4*)d_out);
    }
}